// Round 1
// 76.534 us; speedup vs baseline: 1.0118x; 1.0118x over previous
//
#include <hip/hip_runtime.h>

// Problem constants (fixed by setup_inputs): N=512 anchors, D=128 dims, K=16.
constexpr int NN = 512;
constexpr int DD = 128;
constexpr int KK = 16;
constexpr int GG = 2;           // anchors per block (one yad sweep serves both)
constexpr int NB = NN / GG;     // 256 blocks -> one per CU, all co-resident
constexpr int NT = 512;         // 8 waves: best measured config (77.8us round 3;
                                // 4-wave variant regressed to 78.3 -- latency
                                // hiding beats ds_read issue-pressure savings)
#define ALPHA 0.1f
#define MAGIC 0x5CA1AB1Eu       // != 0xAAAAAAAA harness poison, != 0
#define SENTINEL (-1.0e30f)     // posd pad: (SENTINEL - dk) + ALPHA < 0 always
#define INVALID_DK (3.0e38f)    // invalid-k dk: (pd - INVALID_DK) + ALPHA < 0,
                                // finite for all real pd (no inf/nan produced)

__global__ __launch_bounds__(NT) void area_loss_fused(
    const float* __restrict__ wid,
    const float* __restrict__ ken,
    const float* __restrict__ lrg,
    const float* __restrict__ sml,
    const float* __restrict__ yad,
    const int*   __restrict__ x,
    float*       __restrict__ out,
    float*       __restrict__ partial,   // d_ws
    unsigned*    __restrict__ flags)     // d_ws + NB floats
{
    __shared__ __align__(16) float yi[GG][DD];   // the block's 2 anchor rows
    __shared__ float    d2[GG][NN];              // distances anchor->all j
                                                 // (consumed only by pos-gather)
    __shared__ unsigned mask[GG][NN / 32];       // membership bitsets
    __shared__ int      xl[GG][KK];              // staged x rows
    __shared__ __align__(16) float posd[GG][KK]; // pos distances, sentinel-padded
    __shared__ int      pcnt[GG];
    __shared__ float    wsum[NT / 64];

    const int b = blockIdx.x;
    const int t = threadIdx.x;
    const int ibase = b * GG;

    // Hoisted hierarchical-term loads (threads 0..255): issue the four
    // HBM-cold global loads NOW so their ~900-cyc latency hides under the
    // distance phase; consumed only after the first __syncthreads sections.
    float hw = 0.f, hk = 0.f, hl = 0.f, hs = 0.f;
    if (t < GG * DD) {
        size_t idx = (size_t)ibase * DD + t;
        hw = wid[idx]; hk = ken[idx]; hl = lrg[idx]; hs = sml[idx];
    }

    // Stage anchors (float4), x rows; init masks/counters; sentinel-fill posd
    // so the hinge loop can run a full compile-time 16 iterations (entries
    // >= pcnt contribute exactly +0.0f through fmaxf).
    if (t < GG * DD / 4)
        ((float4*)yi)[t] = ((const float4*)(yad + (size_t)ibase * DD))[t];
    if (t < GG * NN / 32) ((unsigned*)mask)[t] = 0u;
    if (t < GG * KK) {
        ((int*)xl)[t] = x[ibase * KK + t];
        ((float*)posd)[t] = SENTINEL;
    }
    if (t < GG)           pcnt[t] = 0;
    __syncthreads();

    // Membership bitmasks (duplicates collapse, matching reference scatter).
    // Runs in the distance region; consumed only after the next barrier.
    if (t < GG * KK) {
        int a = t / KK;
        int j = xl[a][t % KK];
        atomicOr(&mask[a][j >> 5], 1u << (j & 31));
    }

    // Distances: thread t owns row j=t (1 row/thread, 8 waves for latency
    // hiding). yi read as float4 -> ds_read_b128, same-address broadcast.
    // a0/a1 stay live in registers: the hinge uses them directly as dk,
    // the LDS copy exists only for the 32-thread pos-gather.
    float a0 = 0.f, a1 = 0.f;
    {
        const float4* row = (const float4*)(yad + (size_t)t * DD);
#pragma unroll
        for (int c = 0; c < DD / 4; ++c) {
            float4 v  = row[c];
            float4 y0 = ((const float4*)yi[0])[c];
            float4 y1 = ((const float4*)yi[1])[c];
            float e;
            e = v.x - y0.x; a0 += e * e;
            e = v.y - y0.y; a0 += e * e;
            e = v.z - y0.z; a0 += e * e;
            e = v.w - y0.w; a0 += e * e;
            e = v.x - y1.x; a1 += e * e;
            e = v.y - y1.y; a1 += e * e;
            e = v.z - y1.z; a1 += e * e;
            e = v.w - y1.w; a1 += e * e;
        }
        d2[0][t] = a0;
        d2[1][t] = a1;
    }
    __syncthreads();

    // Pos-set gather: first occurrence only (dedup), j != anchor.
    if (t < GG * KK) {
        int a = t / KK, e = t % KK;
        int j = xl[a][e];
        bool ok = (j != ibase + a);
        for (int q = 0; q < e && ok; ++q)
            if (xl[a][q] == j) ok = false;
        if (ok) {
            int p = atomicAdd(&pcnt[a], 1);
            posd[a][p] = d2[a][j];
        }
    }
    __syncthreads();

    float acc = 0.f;

    // Triplet hinge: thread t owns neg-candidate k=t for each anchor.
    // Branchless + fully unrolled: posd preloaded via 4 broadcast
    // ds_read_b128 per anchor (no per-iteration LDS dependency), invalid k
    // neutralized by dk=INVALID_DK (adds exact zeros). Expression order
    // (pd - dk) + ALPHA and the single sequential acc chain are kept
    // identical to the reference-matching original (absmax must stay 0.0).
    const float dreg2[GG] = {a0, a1};
#pragma unroll
    for (int a = 0; a < GG; ++a) {
        const int ia = ibase + a;
        const bool valid =
            (t != ia) && !((mask[a][t >> 5] >> (t & 31)) & 1u);
        const float dk = valid ? dreg2[a] : INVALID_DK;
        float4 q0 = ((const float4*)posd[a])[0];
        float4 q1 = ((const float4*)posd[a])[1];
        float4 q2 = ((const float4*)posd[a])[2];
        float4 q3 = ((const float4*)posd[a])[3];
        const float pd[KK] = {q0.x, q0.y, q0.z, q0.w,
                              q1.x, q1.y, q1.z, q1.w,
                              q2.x, q2.y, q2.z, q2.w,
                              q3.x, q3.y, q3.z, q3.w};
#pragma unroll
        for (int p = 0; p < KK; ++p)
            acc += fmaxf(pd[p] - dk + ALPHA, 0.f);
    }

    // Hierarchical term (values already loaded at kernel top).
    if (t < GG * DD) {
        float y = ((float*)yi)[t];
        float p0 = hw - hk, p1 = hw - hl, p2 = hl - hs, p3 = hs - y;
        acc += p0 * p0 + p1 * p1 + p2 * p2 + p3 * p3;
    }

    // Block reduction: shuffle within wave-64, LDS across 8 waves.
    for (int off = 32; off; off >>= 1) acc += __shfl_down(acc, off, 64);
    if ((t & 63) == 0) wsum[t >> 6] = acc;
    __syncthreads();

    if (b != 0) {
        if (t == 0) {
            float s = 0.f;
#pragma unroll
            for (int w = 0; w < NT / 64; ++w) s += wsum[w];
            partial[b] = s;
            // Release: partial[b] visible device-wide before flag flips.
            __hip_atomic_store(&flags[b], MAGIC, __ATOMIC_RELEASE,
                               __HIP_MEMORY_SCOPE_AGENT);
        }
    } else {
        // Block 0: own sum, then gather the other 255 partials via flag spin.
        float mine = 0.f;
        if (t == 0) {
#pragma unroll
            for (int w = 0; w < NT / 64; ++w) mine += wsum[w];
        }
        __syncthreads();  // t0 done with wsum before reuse

        float other = 0.f;
        if (t >= 1 && t < NB) {
            while (__hip_atomic_load(&flags[t], __ATOMIC_ACQUIRE,
                                     __HIP_MEMORY_SCOPE_AGENT) != MAGIC) {
                __builtin_amdgcn_s_sleep(1);
            }
            other = partial[t];
        }
        float tot = mine + other;
        for (int off = 32; off; off >>= 1) tot += __shfl_down(tot, off, 64);
        if ((t & 63) == 0) wsum[t >> 6] = tot;
        __syncthreads();
        if (t == 0) {
            float s = 0.f;
#pragma unroll
            for (int w = 0; w < NT / 64; ++w) s += wsum[w];
            out[0] = s;
        }
    }
}

extern "C" void kernel_launch(void* const* d_in, const int* in_sizes, int n_in,
                              void* d_out, int out_size, void* d_ws, size_t ws_size,
                              hipStream_t stream) {
    const float* wid = (const float*)d_in[0];
    const float* ken = (const float*)d_in[1];
    const float* lrg = (const float*)d_in[2];
    const float* sml = (const float*)d_in[3];
    const float* yad = (const float*)d_in[4];
    const int*   x   = (const int*)d_in[5];
    float*    out     = (float*)d_out;
    float*    partial = (float*)d_ws;              // NB floats
    unsigned* flags   = (unsigned*)(partial + NB); // NB words; poison != MAGIC

    area_loss_fused<<<NB, NT, 0, stream>>>(wid, ken, lrg, sml, yad, x,
                                           out, partial, flags);
}